// Round 1
// baseline (2337.027 us; speedup 1.0000x reference)
//
#include <hip/hip_runtime.h>
#include <cstddef>

#define F 256
#define H 256
#define NSTRUCT 1000
#define NSPEC 4
#define TM 32

// ---------------- small prep kernels ----------------

__global__ void transpose_weights(const float* __restrict__ W, float* __restrict__ WT) {
  // W: [S, F, H] (f major, j minor) -> WT: [S, H, F]  (WT[s][j][f] = W[s][f][j])
  int idx = blockIdx.x * blockDim.x + threadIdx.x;
  if (idx >= NSPEC * F * H) return;
  int s = idx / (F * H);
  int r = idx % (F * H);
  int j = r / F;
  int f = r % F;
  WT[idx] = W[s * F * H + f * H + j];
}

__global__ void histogram_kernel(const int* __restrict__ z, int* __restrict__ cnt, int N) {
  int i = blockIdx.x * blockDim.x + threadIdx.x;
  if (i < N) atomicAdd(&cnt[z[i]], 1);
}

__global__ void scan_kernel(int* __restrict__ cnt, int* __restrict__ poff) {
  // single thread: padded exclusive scan; reset cnt for use as scatter cursors
  int acc = 0;
  for (int s = 0; s < NSPEC; ++s) {
    poff[s] = acc;
    int padded = ((cnt[s] + TM - 1) / TM) * TM;
    acc += padded;
    cnt[s] = 0;
  }
  poff[NSPEC] = acc;
}

__global__ void scatter_kernel(const int* __restrict__ z, const int* __restrict__ poff,
                               int* __restrict__ cnt, int* __restrict__ perm, int N) {
  int i = blockIdx.x * blockDim.x + threadIdx.x;
  if (i < N) {
    int s = z[i];
    int pos = poff[s] + atomicAdd(&cnt[s], 1);
    perm[pos] = i;
  }
}

// ---------------- fused MLP fwd+bwd ----------------

__device__ __forceinline__ void gemm_tile(const float (*S)[256], const float* __restrict__ w,
                                          int tr, int tc, float acc[4][8]) {
  #pragma unroll
  for (int i = 0; i < 4; ++i)
    #pragma unroll
    for (int j = 0; j < 8; ++j) acc[i][j] = 0.f;
  #pragma unroll 4
  for (int k = 0; k < 256; ++k) {
    float xv0 = S[tr * 4 + 0][k];
    float xv1 = S[tr * 4 + 1][k];
    float xv2 = S[tr * 4 + 2][k];
    float xv3 = S[tr * 4 + 3][k];
    const float4 wa = *(const float4*)(w + (size_t)k * 256 + tc * 8);
    const float4 wb = *(const float4*)(w + (size_t)k * 256 + tc * 8 + 4);
    float wv[8] = {wa.x, wa.y, wa.z, wa.w, wb.x, wb.y, wb.z, wb.w};
    #pragma unroll
    for (int j = 0; j < 8; ++j) {
      acc[0][j] += xv0 * wv[j];
      acc[1][j] += xv1 * wv[j];
      acc[2][j] += xv2 * wv[j];
      acc[3][j] += xv3 * wv[j];
    }
  }
}

__global__ __launch_bounds__(256, 2) void mlp_fused(
    const float* __restrict__ X,
    const int* __restrict__ smap,
    const float* __restrict__ W1g, const float* __restrict__ b1g,
    const float* __restrict__ W2g, const float* __restrict__ b2g,
    const float* __restrict__ W3g, const float* __restrict__ b3g,
    const float* __restrict__ Wskipg, const float* __restrict__ bskipg,
    const float* __restrict__ W1T, const float* __restrict__ W2T,
    const int* __restrict__ perm, const int* __restrict__ poff,
    float* __restrict__ energies, float* __restrict__ nng)
{
  __shared__ float A[TM][256];   // X, then H2/d2
  __shared__ float B[TM][256];   // H1, then d1
  __shared__ float xskp[TM][8];
  __shared__ float ypart[TM][8];

  const int tid = threadIdx.x;
  const int row0 = blockIdx.x * TM;
  if (row0 >= poff[NSPEC]) return;

  int s = 0;
  #pragma unroll
  for (int q = 1; q < NSPEC; ++q)
    if (row0 >= poff[q]) s = q;

  const float* w1  = W1g + (size_t)s * F * H;
  const float* w2  = W2g + (size_t)s * H * H;
  const float* w1t = W1T + (size_t)s * F * H;
  const float* w2t = W2T + (size_t)s * H * H;
  const float* w3  = W3g + s * H;
  const float* wsk = Wskipg + s * F;
  const float b3v  = b3g[s];
  const float bskv = bskipg[s];

  // ---- phase 1: gather X tile + skip-connection partial dots ----
  const int lr = tid >> 3;  // 0..31 row
  const int lc = tid & 7;   // 0..7  (8 threads per row, strided float4 slots)
  const int atomR = perm[row0 + lr];
  float xsk = 0.f;
  if (atomR >= 0) {
    const float4* xrow = (const float4*)(X + (size_t)atomR * F);
    #pragma unroll
    for (int jj = 0; jj < 8; ++jj) {
      const int fi = lc + jj * 8;
      float4 v = xrow[fi];
      *(float4*)&A[lr][fi * 4] = v;
      float4 wv = ((const float4*)wsk)[fi];
      xsk += v.x * wv.x + v.y * wv.y + v.z * wv.z + v.w * wv.w;
    }
  } else {
    float4 zed = make_float4(0.f, 0.f, 0.f, 0.f);
    #pragma unroll
    for (int jj = 0; jj < 8; ++jj) *(float4*)&A[lr][(lc + jj * 8) * 4] = zed;
  }
  xskp[lr][lc] = xsk;
  __syncthreads();

  const int tr = tid >> 5;  // 0..7: rows tr*4 .. tr*4+3
  const int tc = tid & 31;  // cols tc*8 .. tc*8+7
  float acc[4][8];

  // ---- GEMM1: H1 = tanh(X @ W1 + b1)  (A -> B) ----
  gemm_tile(A, w1, tr, tc, acc);
  {
    const float4 ba = *(const float4*)&b1g[s * H + tc * 8];
    const float4 bb = *(const float4*)&b1g[s * H + tc * 8 + 4];
    float bv[8] = {ba.x, ba.y, ba.z, ba.w, bb.x, bb.y, bb.z, bb.w};
    #pragma unroll
    for (int i = 0; i < 4; ++i)
      #pragma unroll
      for (int j = 0; j < 8; ++j)
        B[tr * 4 + i][tc * 8 + j] = tanhf(acc[i][j] + bv[j]);
  }
  __syncthreads();

  // ---- GEMM2: H2 = tanh(H1 @ W2 + b2)  (B -> A) ----
  gemm_tile(B, w2, tr, tc, acc);
  {
    const float4 ba = *(const float4*)&b2g[s * H + tc * 8];
    const float4 bb = *(const float4*)&b2g[s * H + tc * 8 + 4];
    float bv[8] = {ba.x, ba.y, ba.z, ba.w, bb.x, bb.y, bb.z, bb.w};
    #pragma unroll
    for (int i = 0; i < 4; ++i)
      #pragma unroll
      for (int j = 0; j < 8; ++j)
        A[tr * 4 + i][tc * 8 + j] = tanhf(acc[i][j] + bv[j]);
  }
  __syncthreads();

  // ---- energies: y = h2 @ W3 + b3 + x @ Wskip + bskip ----
  {
    float part = 0.f;
    #pragma unroll
    for (int q = 0; q < 8; ++q) {
      int j4 = lc * 8 + q;
      float4 h2v = *(const float4*)&A[lr][j4 * 4];
      float4 w3v = ((const float4*)w3)[j4];
      part += h2v.x * w3v.x + h2v.y * w3v.y + h2v.z * w3v.z + h2v.w * w3v.w;
    }
    ypart[lr][lc] = part;
  }
  __syncthreads();

  // ---- d2 = (1 - h2^2) * W3  (A in place), finalize y ----
  {
    const float4 wa = *(const float4*)&w3[tc * 8];
    const float4 wb = *(const float4*)&w3[tc * 8 + 4];
    float w3v[8] = {wa.x, wa.y, wa.z, wa.w, wb.x, wb.y, wb.z, wb.w};
    #pragma unroll
    for (int i = 0; i < 4; ++i)
      #pragma unroll
      for (int j = 0; j < 8; ++j) {
        float v = A[tr * 4 + i][tc * 8 + j];
        A[tr * 4 + i][tc * 8 + j] = (1.f - v * v) * w3v[j];
      }
  }
  if (lc == 0 && atomR >= 0) {
    float ysum = b3v + bskv;
    #pragma unroll
    for (int q = 0; q < 8; ++q) ysum += ypart[lr][q] + xskp[lr][q];
    atomicAdd(&energies[smap[atomR]], ysum);
  }
  __syncthreads();

  // ---- GEMM3: g1 = d2 @ W2^T;  d1 = (1 - h1^2) * g1  (A -> B) ----
  gemm_tile(A, w2t, tr, tc, acc);
  {
    #pragma unroll
    for (int i = 0; i < 4; ++i)
      #pragma unroll
      for (int j = 0; j < 8; ++j) {
        float h = B[tr * 4 + i][tc * 8 + j];
        B[tr * 4 + i][tc * 8 + j] = (1.f - h * h) * acc[i][j];
      }
  }
  __syncthreads();

  // ---- GEMM4: dE/dx = d1 @ W1^T + Wskip  (B -> global nn_grads) ----
  gemm_tile(B, w1t, tr, tc, acc);
  {
    const float4 wa = *(const float4*)&wsk[tc * 8];
    const float4 wb = *(const float4*)&wsk[tc * 8 + 4];
    float wv[8] = {wa.x, wa.y, wa.z, wa.w, wb.x, wb.y, wb.z, wb.w};
    #pragma unroll
    for (int i = 0; i < 4; ++i) {
      int a2 = perm[row0 + tr * 4 + i];
      if (a2 >= 0) {
        float4 o1 = make_float4(acc[i][0] + wv[0], acc[i][1] + wv[1],
                                acc[i][2] + wv[2], acc[i][3] + wv[3]);
        float4 o2 = make_float4(acc[i][4] + wv[4], acc[i][5] + wv[5],
                                acc[i][6] + wv[6], acc[i][7] + wv[7]);
        *(float4*)&nng[(size_t)a2 * F + tc * 8]     = o1;
        *(float4*)&nng[(size_t)a2 * F + tc * 8 + 4] = o2;
      }
    }
  }
}

// ---------------- forces: one wave per pair ----------------

__global__ __launch_bounds__(256) void force_kernel(
    const float* __restrict__ ptg, const int* __restrict__ gmap,
    const float* __restrict__ g, float* __restrict__ forces, int P)
{
  int w = (int)((blockIdx.x * 256 + threadIdx.x) >> 6);
  int lane = threadIdx.x & 63;
  if (w >= P) return;
  int a = gmap[w];
  float4 gv = ((const float4*)(g + (size_t)a * F))[lane];
  const float4* gr = (const float4*)(ptg + (size_t)w * 3 * F);
  float s0, s1, s2;
  {
    float4 t = gr[0 * 64 + lane];
    s0 = t.x * gv.x + t.y * gv.y + t.z * gv.z + t.w * gv.w;
    t = gr[1 * 64 + lane];
    s1 = t.x * gv.x + t.y * gv.y + t.z * gv.z + t.w * gv.w;
    t = gr[2 * 64 + lane];
    s2 = t.x * gv.x + t.y * gv.y + t.z * gv.z + t.w * gv.w;
  }
  #pragma unroll
  for (int off = 32; off >= 1; off >>= 1) {
    s0 += __shfl_xor(s0, off, 64);
    s1 += __shfl_xor(s1, off, 64);
    s2 += __shfl_xor(s2, off, 64);
  }
  float r = (lane == 0) ? s0 : ((lane == 1) ? s1 : s2);
  if (lane < 3) atomicAdd(&forces[(size_t)a * 3 + lane], -r);
}

// ---------------- launch ----------------

extern "C" void kernel_launch(void* const* d_in, const int* in_sizes, int n_in,
                              void* d_out, int out_size, void* d_ws, size_t ws_size,
                              hipStream_t stream) {
  const float* X     = (const float*)d_in[0];
  const int*   z     = (const int*)d_in[1];
  const int*   smap  = (const int*)d_in[2];
  const float* ptg   = (const float*)d_in[3];
  const int*   gmap  = (const int*)d_in[4];
  const float* W1    = (const float*)d_in[5];
  const float* b1    = (const float*)d_in[6];
  const float* W2    = (const float*)d_in[7];
  const float* b2    = (const float*)d_in[8];
  const float* W3    = (const float*)d_in[9];
  const float* b3    = (const float*)d_in[10];
  const float* Wskip = (const float*)d_in[11];
  const float* bskip = (const float*)d_in[12];

  const int N = in_sizes[1];
  const int P = in_sizes[4];

  // workspace layout (needs ~106 MB):
  char* ws = (char*)d_ws;
  int* cnt  = (int*)ws;            // 4 ints
  int* poff = (int*)(ws + 16);     // 5 ints (padded species offsets)
  int* perm = (int*)(ws + 64);
  size_t perm_bytes = (size_t)(N + NSPEC * TM) * sizeof(int);
  size_t off = 64 + perm_bytes;
  off = (off + 255) & ~(size_t)255;
  float* W1T = (float*)(ws + off); off += (size_t)NSPEC * F * H * sizeof(float);
  float* W2T = (float*)(ws + off); off += (size_t)NSPEC * F * H * sizeof(float);
  float* nng = (float*)(ws + off); // N * F floats

  float* energies = (float*)d_out;
  float* forces   = energies + NSTRUCT;

  hipMemsetAsync(d_out, 0, (size_t)out_size * sizeof(float), stream);
  hipMemsetAsync(cnt, 0, 16, stream);
  hipMemsetAsync(perm, 0xFF, perm_bytes, stream);  // -1 sentinel (padding rows)

  transpose_weights<<<(NSPEC * F * H + 255) / 256, 256, 0, stream>>>(W1, W1T);
  transpose_weights<<<(NSPEC * F * H + 255) / 256, 256, 0, stream>>>(W2, W2T);
  histogram_kernel<<<(N + 255) / 256, 256, 0, stream>>>(z, cnt, N);
  scan_kernel<<<1, 1, 0, stream>>>(cnt, poff);
  scatter_kernel<<<(N + 255) / 256, 256, 0, stream>>>(z, poff, cnt, perm, N);

  int mlpBlocks = (N + TM - 1) / TM + NSPEC;
  mlp_fused<<<mlpBlocks, 256, 0, stream>>>(X, smap, W1, b1, W2, b2, W3, b3,
                                           Wskip, bskip, W1T, W2T, perm, poff,
                                           energies, nng);

  int forceBlocks = (int)(((size_t)P * 64 + 255) / 256);
  force_kernel<<<forceBlocks, 256, 0, stream>>>(ptg, gmap, nng, forces, P);
}

// Round 2
// 511.364 us; speedup vs baseline: 4.5702x; 4.5702x over previous
//
#include <hip/hip_runtime.h>
#include <cstddef>

#define F 256
#define H 256
#define NSTRUCT 1000
#define NSPEC 4
#define TM 32
#define PAD 264  // 256 + 8 bf16 pad -> conflict-free ds_read_b128

typedef __attribute__((ext_vector_type(8))) short bf16x8;
typedef __attribute__((ext_vector_type(4))) float f32x4;

__device__ __forceinline__ unsigned short f2bf(float v) {
  unsigned int u = __float_as_uint(v);
  unsigned int r = (u + 0x7FFFu + ((u >> 16) & 1u)) >> 16;  // RNE
  return (unsigned short)r;
}

__device__ __forceinline__ float tanh_fast(float x) {
  x = fminf(fmaxf(x, -15.f), 15.f);
  float e = __expf(2.f * x);
  return __fdividef(e - 1.f, e + 1.f);
}

// ---------------- prep kernels ----------------

// Pack weights into bf16 MFMA-fragment order:
// Out[s][jt][kk][lane][i] = W[k][j]   (k = kk*32 + (lane>>4)*8 + i, j = jt*16 + (lane&15))
// trans=1 reads In[j][k] (i.e. packs In^T).
__global__ void prep_w(const float* __restrict__ In, unsigned short* __restrict__ Out, int trans) {
  int t = blockIdx.x * 256 + threadIdx.x;
  if (t >= NSPEC * 8192) return;
  int lane = t & 63, kk = (t >> 6) & 7, jt = (t >> 9) & 15, s = t >> 13;
  int j = jt * 16 + (lane & 15);
  int k0 = kk * 32 + (lane >> 4) * 8;
  const float* base = In + (size_t)s * F * H;
  unsigned short o[8];
  #pragma unroll
  for (int i = 0; i < 8; ++i) {
    int k = k0 + i;
    float v = trans ? base[(size_t)j * 256 + k] : base[(size_t)k * 256 + j];
    o[i] = f2bf(v);
  }
  *(ushort4*)(Out + (size_t)t * 8) = make_ushort4(o[0], o[1], o[2], o[3]);
  *(ushort4*)(Out + (size_t)t * 8 + 4) = make_ushort4(o[4], o[5], o[6], o[7]);
}

__global__ void histogram_kernel(const int* __restrict__ z, int* __restrict__ cnt, int N) {
  int i = blockIdx.x * blockDim.x + threadIdx.x;
  int lane = threadIdx.x & 63;
  int zi = (i < N) ? z[i] : -1;
  #pragma unroll
  for (int s = 0; s < NSPEC; ++s) {
    unsigned long long m = __ballot(zi == s);
    if (m != 0ull && lane == __ffsll((unsigned long long)m) - 1)
      atomicAdd(&cnt[s], __popcll(m));
  }
}

__global__ void scan_kernel(int* __restrict__ cnt, int* __restrict__ poff) {
  int acc = 0;
  for (int s = 0; s < NSPEC; ++s) {
    poff[s] = acc;
    int padded = ((cnt[s] + TM - 1) / TM) * TM;
    acc += padded;
    cnt[s] = 0;
  }
  poff[NSPEC] = acc;
}

__global__ void scatter_kernel(const int* __restrict__ z, const int* __restrict__ poff,
                               int* __restrict__ cnt, int* __restrict__ perm, int N) {
  int i = blockIdx.x * blockDim.x + threadIdx.x;
  int lane = threadIdx.x & 63;
  int zi = (i < N) ? z[i] : -1;
  #pragma unroll
  for (int s = 0; s < NSPEC; ++s) {
    unsigned long long m = __ballot(zi == s);
    if (m == 0ull) continue;
    int leader = __ffsll((unsigned long long)m) - 1;
    int base = 0;
    if (lane == leader) base = atomicAdd(&cnt[s], __popcll(m));
    base = __shfl(base, leader, 64);
    if (zi == s) {
      int rank = __popcll(m & ((1ull << lane) - 1ull));
      perm[poff[s] + base + rank] = i;
    }
  }
}

// ---------------- fused MFMA MLP fwd+bwd ----------------

// One 32x256 @ 256x256 GEMM tile: 4 waves, wave w -> col-tiles w*4..w*4+3, both row-tiles.
__device__ __forceinline__ void gemm32(const unsigned short (*src)[PAD],
                                       const unsigned short* __restrict__ wf,
                                       int w, int lane, f32x4 acc[2][4]) {
  const int l15 = lane & 15, lk = lane >> 4;
  #pragma unroll
  for (int rt = 0; rt < 2; ++rt)
    #pragma unroll
    for (int q = 0; q < 4; ++q) acc[rt][q] = (f32x4){0.f, 0.f, 0.f, 0.f};
  #pragma unroll
  for (int kk = 0; kk < 8; ++kk) {
    const int kcol = kk * 32 + lk * 8;
    bf16x8 a0 = *(const bf16x8*)&src[l15][kcol];
    bf16x8 a1 = *(const bf16x8*)&src[16 + l15][kcol];
    #pragma unroll
    for (int q = 0; q < 4; ++q) {
      const int jt = w * 4 + q;
      bf16x8 b = *(const bf16x8*)(wf + ((size_t)(jt * 8 + kk) * 64 + lane) * 8);
      acc[0][q] = __builtin_amdgcn_mfma_f32_16x16x32_bf16(a0, b, acc[0][q], 0, 0, 0);
      acc[1][q] = __builtin_amdgcn_mfma_f32_16x16x32_bf16(a1, b, acc[1][q], 0, 0, 0);
    }
  }
}

__global__ __launch_bounds__(256, 2) void mlp_fused(
    const float* __restrict__ X, const int* __restrict__ smap,
    const unsigned short* __restrict__ Wf,
    const float* __restrict__ b1g, const float* __restrict__ b2g,
    const float* __restrict__ W3g, const float* __restrict__ b3g,
    const float* __restrict__ Wskipg, const float* __restrict__ bskipg,
    const int* __restrict__ perm, const int* __restrict__ poff,
    float* __restrict__ energies, float* __restrict__ nng)
{
  __shared__ __align__(16) unsigned short bufA[TM][PAD];
  __shared__ __align__(16) unsigned short bufB[TM][PAD];
  __shared__ float xskp[TM][8];
  __shared__ float e_lds[TM];
  __shared__ int atom_l[TM];

  const int tid = threadIdx.x;
  const int row0 = blockIdx.x * TM;
  if (row0 >= poff[NSPEC]) return;

  int s = 0;
  #pragma unroll
  for (int q = 1; q < NSPEC; ++q)
    if (row0 >= poff[q]) s = q;

  const int WMAT = NSPEC * 65536;
  const unsigned short* w1f  = Wf + (size_t)s * 65536;
  const unsigned short* w2f  = Wf + (size_t)WMAT + (size_t)s * 65536;
  const unsigned short* w2tf = Wf + 2 * (size_t)WMAT + (size_t)s * 65536;
  const unsigned short* w1tf = Wf + 3 * (size_t)WMAT + (size_t)s * 65536;
  const float* wsk = Wskipg + s * F;

  // ---- phase 0: gather X tile (fp32->bf16), skip-dot partials ----
  {
    const int lr = tid >> 3, lc = tid & 7;
    if (tid < TM) { e_lds[tid] = 0.f; atom_l[tid] = perm[row0 + tid]; }
    const int atomR = perm[row0 + lr];
    float xsk = 0.f;
    if (atomR >= 0) {
      const float4* xrow = (const float4*)(X + (size_t)atomR * F);
      #pragma unroll
      for (int jj = 0; jj < 8; ++jj) {
        const int fi = lc + jj * 8;
        float4 v = xrow[fi];
        float4 wv = ((const float4*)wsk)[fi];
        xsk += v.x * wv.x + v.y * wv.y + v.z * wv.z + v.w * wv.w;
        *(ushort4*)&bufA[lr][fi * 4] =
            make_ushort4(f2bf(v.x), f2bf(v.y), f2bf(v.z), f2bf(v.w));
      }
    } else {
      #pragma unroll
      for (int jj = 0; jj < 8; ++jj)
        *(ushort4*)&bufA[lr][(lc + jj * 8) * 4] = make_ushort4(0, 0, 0, 0);
    }
    xskp[lr][lc] = xsk;
  }
  __syncthreads();

  const int w = tid >> 6, lane = tid & 63;
  const int l15 = lane & 15, lk = lane >> 4;
  f32x4 acc[2][4];
  float t1[2][4][4];  // 1 - h1^2, layout-matched to GEMM3 output

  // ---- GEMM1: h1 = tanh(X @ W1 + b1) ----
  gemm32(bufA, w1f, w, lane, acc);
  #pragma unroll
  for (int q = 0; q < 4; ++q) {
    const int col = w * 64 + q * 16 + l15;
    const float b1v = b1g[s * H + col];
    #pragma unroll
    for (int rt = 0; rt < 2; ++rt)
      #pragma unroll
      for (int r = 0; r < 4; ++r) {
        float h = tanh_fast(acc[rt][q][r] + b1v);
        t1[rt][q][r] = 1.f - h * h;
        bufB[rt * 16 + lk * 4 + r][col] = f2bf(h);
      }
  }
  __syncthreads();

  // ---- GEMM2: h2 = tanh(h1 @ W2 + b2); energy partials; d2 = (1-h2^2)*W3 ----
  gemm32(bufB, w2f, w, lane, acc);
  {
    float ep[2][4];
    #pragma unroll
    for (int rt = 0; rt < 2; ++rt)
      #pragma unroll
      for (int r = 0; r < 4; ++r) ep[rt][r] = 0.f;
    #pragma unroll
    for (int q = 0; q < 4; ++q) {
      const int col = w * 64 + q * 16 + l15;
      const float b2v = b2g[s * H + col];
      const float w3v = W3g[s * H + col];
      #pragma unroll
      for (int rt = 0; rt < 2; ++rt)
        #pragma unroll
        for (int r = 0; r < 4; ++r) {
          float h = tanh_fast(acc[rt][q][r] + b2v);
          ep[rt][r] += h * w3v;
          bufA[rt * 16 + lk * 4 + r][col] = f2bf((1.f - h * h) * w3v);
        }
    }
    #pragma unroll
    for (int rt = 0; rt < 2; ++rt)
      #pragma unroll
      for (int r = 0; r < 4; ++r) {
        #pragma unroll
        for (int m = 1; m <= 8; m <<= 1)
          ep[rt][r] += __shfl_xor(ep[rt][r], m, 64);
      }
    if (l15 == 0) {
      #pragma unroll
      for (int rt = 0; rt < 2; ++rt)
        #pragma unroll
        for (int r = 0; r < 4; ++r)
          atomicAdd(&e_lds[rt * 16 + lk * 4 + r], ep[rt][r]);
    }
  }
  __syncthreads();

  // ---- energies finalize (32 threads) ----
  if (tid < TM) {
    int atom = atom_l[tid];
    if (atom >= 0) {
      float xs = 0.f;
      #pragma unroll
      for (int q = 0; q < 8; ++q) xs += xskp[tid][q];
      atomicAdd(&energies[smap[atom]], e_lds[tid] + xs + b3g[s] + bskipg[s]);
    }
  }

  // ---- GEMM3: g1 = d2 @ W2^T; d1 = (1-h1^2)*g1 ----
  gemm32(bufA, w2tf, w, lane, acc);
  #pragma unroll
  for (int q = 0; q < 4; ++q) {
    const int col = w * 64 + q * 16 + l15;
    #pragma unroll
    for (int rt = 0; rt < 2; ++rt)
      #pragma unroll
      for (int r = 0; r < 4; ++r)
        bufB[rt * 16 + lk * 4 + r][col] = f2bf(t1[rt][q][r] * acc[rt][q][r]);
  }
  __syncthreads();

  // ---- GEMM4: dE/dx = d1 @ W1^T + Wskip -> nng ----
  gemm32(bufB, w1tf, w, lane, acc);
  #pragma unroll
  for (int q = 0; q < 4; ++q) {
    const int col = w * 64 + q * 16 + l15;
    const float wv = wsk[col];
    #pragma unroll
    for (int rt = 0; rt < 2; ++rt)
      #pragma unroll
      for (int r = 0; r < 4; ++r) {
        int atom2 = atom_l[rt * 16 + lk * 4 + r];
        if (atom2 >= 0) nng[(size_t)atom2 * F + col] = acc[rt][q][r] + wv;
      }
  }
}

// ---------------- forces: one wave per pair ----------------

__global__ __launch_bounds__(256) void force_kernel(
    const float* __restrict__ ptg, const int* __restrict__ gmap,
    const float* __restrict__ g, float* __restrict__ forces, int P)
{
  int w = (int)((blockIdx.x * 256 + threadIdx.x) >> 6);
  int lane = threadIdx.x & 63;
  if (w >= P) return;
  int a = gmap[w];
  float4 gv = ((const float4*)(g + (size_t)a * F))[lane];
  const float4* gr = (const float4*)(ptg + (size_t)w * 3 * F);
  float s0, s1, s2;
  {
    float4 t = gr[0 * 64 + lane];
    s0 = t.x * gv.x + t.y * gv.y + t.z * gv.z + t.w * gv.w;
    t = gr[1 * 64 + lane];
    s1 = t.x * gv.x + t.y * gv.y + t.z * gv.z + t.w * gv.w;
    t = gr[2 * 64 + lane];
    s2 = t.x * gv.x + t.y * gv.y + t.z * gv.z + t.w * gv.w;
  }
  #pragma unroll
  for (int off = 32; off >= 1; off >>= 1) {
    s0 += __shfl_xor(s0, off, 64);
    s1 += __shfl_xor(s1, off, 64);
    s2 += __shfl_xor(s2, off, 64);
  }
  float r = (lane == 0) ? s0 : ((lane == 1) ? s1 : s2);
  if (lane < 3) atomicAdd(&forces[(size_t)a * 3 + lane], -r);
}

// ---------------- launch ----------------

extern "C" void kernel_launch(void* const* d_in, const int* in_sizes, int n_in,
                              void* d_out, int out_size, void* d_ws, size_t ws_size,
                              hipStream_t stream) {
  const float* X     = (const float*)d_in[0];
  const int*   z     = (const int*)d_in[1];
  const int*   smap  = (const int*)d_in[2];
  const float* ptg   = (const float*)d_in[3];
  const int*   gmap  = (const int*)d_in[4];
  const float* W1    = (const float*)d_in[5];
  const float* b1    = (const float*)d_in[6];
  const float* W2    = (const float*)d_in[7];
  const float* b2    = (const float*)d_in[8];
  const float* W3    = (const float*)d_in[9];
  const float* b3    = (const float*)d_in[10];
  const float* Wskip = (const float*)d_in[11];
  const float* bskip = (const float*)d_in[12];

  const int N = in_sizes[1];
  const int P = in_sizes[4];

  char* ws = (char*)d_ws;
  int* cnt  = (int*)ws;
  int* poff = (int*)(ws + 16);
  int* perm = (int*)(ws + 64);
  size_t perm_bytes = (size_t)(N + NSPEC * TM) * sizeof(int);
  size_t off = 64 + perm_bytes;
  off = (off + 255) & ~(size_t)255;
  unsigned short* Wf = (unsigned short*)(ws + off);
  const size_t WMAT = (size_t)NSPEC * 65536;  // elements per packed matrix
  off += 4 * WMAT * sizeof(unsigned short);
  off = (off + 255) & ~(size_t)255;
  float* nng = (float*)(ws + off);  // N * F floats

  float* energies = (float*)d_out;
  float* forces   = energies + NSTRUCT;

  hipMemsetAsync(d_out, 0, (size_t)out_size * sizeof(float), stream);
  hipMemsetAsync(cnt, 0, 16, stream);
  hipMemsetAsync(perm, 0xFF, perm_bytes, stream);

  int wBlocks = (NSPEC * 8192 + 255) / 256;
  prep_w<<<wBlocks, 256, 0, stream>>>(W1, Wf + 0 * WMAT, 0);
  prep_w<<<wBlocks, 256, 0, stream>>>(W2, Wf + 1 * WMAT, 0);
  prep_w<<<wBlocks, 256, 0, stream>>>(W2, Wf + 2 * WMAT, 1);
  prep_w<<<wBlocks, 256, 0, stream>>>(W1, Wf + 3 * WMAT, 1);

  histogram_kernel<<<(N + 255) / 256, 256, 0, stream>>>(z, cnt, N);
  scan_kernel<<<1, 1, 0, stream>>>(cnt, poff);
  scatter_kernel<<<(N + 255) / 256, 256, 0, stream>>>(z, poff, cnt, perm, N);

  int mlpBlocks = (N + TM - 1) / TM + NSPEC;
  mlp_fused<<<mlpBlocks, 256, 0, stream>>>(X, smap, Wf, b1, b2, W3, b3,
                                           Wskip, bskip, perm, poff,
                                           energies, nng);

  int forceBlocks = (int)(((size_t)P * 64 + 255) / 256);
  force_kernel<<<forceBlocks, 256, 0, stream>>>(ptg, gmap, nng, forces, P);
}

// Round 3
// 411.123 us; speedup vs baseline: 5.6845x; 1.2438x over previous
//
#include <hip/hip_runtime.h>
#include <cstddef>

#define F 256
#define H 256
#define NSTRUCT 1000
#define NSPEC 4
#define TM 64
#define PAD 264  // 256 + 8 bf16 pad -> conflict-free ds_read_b128

typedef __attribute__((ext_vector_type(8))) short bf16x8;
typedef __attribute__((ext_vector_type(4))) float f32x4;

__device__ __forceinline__ unsigned short f2bf(float v) {
  unsigned int u = __float_as_uint(v);
  unsigned int r = (u + 0x7FFFu + ((u >> 16) & 1u)) >> 16;  // RNE
  return (unsigned short)r;
}

__device__ __forceinline__ float bf2f(unsigned short v) {
  return __uint_as_float(((unsigned int)v) << 16);
}

__device__ __forceinline__ float tanh_fast(float x) {
  x = fminf(fmaxf(x, -15.f), 15.f);
  float e = __expf(2.f * x);
  return __fdividef(e - 1.f, e + 1.f);
}

// ---------------- prep kernels ----------------

// Pack all 4 weight matrices (W1, W2, W2^T, W1^T) into bf16 MFMA-fragment order:
// Out[m][s][jt][kk][lane][i] = W[k][j]  (k = kk*32+(lane>>4)*8+i, j = jt*16+(lane&15))
__global__ void prep_w(const float* __restrict__ W1, const float* __restrict__ W2,
                       unsigned short* __restrict__ Out) {
  int t = blockIdx.x * 256 + threadIdx.x;
  if (t >= 4 * NSPEC * 8192) return;
  int m = t >> 15;              // 0:W1 1:W2 2:W2^T 3:W1^T
  int u = t & 32767;
  int lane = u & 63, kk = (u >> 6) & 7, jt = (u >> 9) & 15, s = u >> 13;
  int trans = (m >= 2);
  const float* In = (m == 0 || m == 3) ? W1 : W2;
  int j = jt * 16 + (lane & 15);
  int k0 = kk * 32 + (lane >> 4) * 8;
  const float* base = In + (size_t)s * F * H;
  unsigned short o[8];
  #pragma unroll
  for (int i = 0; i < 8; ++i) {
    int k = k0 + i;
    float v = trans ? base[(size_t)j * 256 + k] : base[(size_t)k * 256 + j];
    o[i] = f2bf(v);
  }
  *(ushort4*)(Out + (size_t)t * 8) = make_ushort4(o[0], o[1], o[2], o[3]);
  *(ushort4*)(Out + (size_t)t * 8 + 4) = make_ushort4(o[4], o[5], o[6], o[7]);
}

__global__ void histogram_kernel(const int* __restrict__ z, int* __restrict__ cnt, int N) {
  int i = blockIdx.x * blockDim.x + threadIdx.x;
  int lane = threadIdx.x & 63;
  int zi = (i < N) ? z[i] : -1;
  #pragma unroll
  for (int s = 0; s < NSPEC; ++s) {
    unsigned long long m = __ballot(zi == s);
    if (m != 0ull && lane == __ffsll((unsigned long long)m) - 1)
      atomicAdd(&cnt[s], __popcll(m));
  }
}

__global__ void scan_kernel(int* __restrict__ cnt, int* __restrict__ poff) {
  int acc = 0;
  for (int s = 0; s < NSPEC; ++s) {
    poff[s] = acc;
    int padded = ((cnt[s] + TM - 1) / TM) * TM;
    acc += padded;
    cnt[s] = 0;
  }
  poff[NSPEC] = acc;
}

__global__ void scatter_kernel(const int* __restrict__ z, const int* __restrict__ poff,
                               int* __restrict__ cnt, int* __restrict__ perm, int N) {
  int i = blockIdx.x * blockDim.x + threadIdx.x;
  int lane = threadIdx.x & 63;
  int zi = (i < N) ? z[i] : -1;
  #pragma unroll
  for (int s = 0; s < NSPEC; ++s) {
    unsigned long long m = __ballot(zi == s);
    if (m == 0ull) continue;
    int leader = __ffsll((unsigned long long)m) - 1;
    int base = 0;
    if (lane == leader) base = atomicAdd(&cnt[s], __popcll(m));
    base = __shfl(base, leader, 64);
    if (zi == s) {
      int rank = __popcll(m & ((1ull << lane) - 1ull));
      perm[poff[s] + base + rank] = i;
    }
  }
}

// ---------------- fused MFMA MLP fwd+bwd ----------------

// 64x256 @ 256x256 tile: 8 waves; wave w -> col-tiles w*2, w*2+1; row-frags 0..3.
__device__ __forceinline__ void gemm64(const unsigned short (*src)[PAD],
                                       const unsigned short* __restrict__ wf,
                                       int w, int lane, f32x4 acc[4][2]) {
  const int l15 = lane & 15, lk = lane >> 4;
  #pragma unroll
  for (int rt = 0; rt < 4; ++rt)
    #pragma unroll
    for (int q = 0; q < 2; ++q) acc[rt][q] = (f32x4){0.f, 0.f, 0.f, 0.f};
  #pragma unroll
  for (int kk = 0; kk < 8; ++kk) {
    const int kcol = kk * 32 + lk * 8;
    bf16x8 a0 = *(const bf16x8*)&src[l15][kcol];
    bf16x8 a1 = *(const bf16x8*)&src[16 + l15][kcol];
    bf16x8 a2 = *(const bf16x8*)&src[32 + l15][kcol];
    bf16x8 a3 = *(const bf16x8*)&src[48 + l15][kcol];
    #pragma unroll
    for (int q = 0; q < 2; ++q) {
      const int jt = w * 2 + q;
      bf16x8 b = *(const bf16x8*)(wf + ((size_t)(jt * 8 + kk) * 64 + lane) * 8);
      acc[0][q] = __builtin_amdgcn_mfma_f32_16x16x32_bf16(a0, b, acc[0][q], 0, 0, 0);
      acc[1][q] = __builtin_amdgcn_mfma_f32_16x16x32_bf16(a1, b, acc[1][q], 0, 0, 0);
      acc[2][q] = __builtin_amdgcn_mfma_f32_16x16x32_bf16(a2, b, acc[2][q], 0, 0, 0);
      acc[3][q] = __builtin_amdgcn_mfma_f32_16x16x32_bf16(a3, b, acc[3][q], 0, 0, 0);
    }
  }
}

__global__ __launch_bounds__(512, 4) void mlp_fused(
    const float* __restrict__ X, const int* __restrict__ smap,
    const unsigned short* __restrict__ Wf,
    const float* __restrict__ b1g, const float* __restrict__ b2g,
    const float* __restrict__ W3g, const float* __restrict__ b3g,
    const float* __restrict__ Wskipg, const float* __restrict__ bskipg,
    const int* __restrict__ perm, const int* __restrict__ poff,
    float* __restrict__ energies, unsigned short* __restrict__ nng)
{
  __shared__ __align__(16) unsigned short bufA[TM][PAD];
  __shared__ __align__(16) unsigned short bufB[TM][PAD];
  __shared__ float xskp[TM][8];
  __shared__ float e_lds[TM];
  __shared__ int atom_l[TM];

  const int tid = threadIdx.x;
  const int row0 = blockIdx.x * TM;
  if (row0 >= poff[NSPEC]) return;

  int s = 0;
  #pragma unroll
  for (int q = 1; q < NSPEC; ++q)
    if (row0 >= poff[q]) s = q;

  const size_t WMAT = (size_t)NSPEC * 65536;
  const unsigned short* w1f  = Wf + (size_t)s * 65536;
  const unsigned short* w2f  = Wf + WMAT + (size_t)s * 65536;
  const unsigned short* w2tf = Wf + 2 * WMAT + (size_t)s * 65536;
  const unsigned short* w1tf = Wf + 3 * WMAT + (size_t)s * 65536;
  const float* wsk = Wskipg + s * F;

  // ---- phase 0: gather X tile (fp32->bf16), skip-dot partials ----
  {
    const int lr = tid >> 3, lc = tid & 7;
    if (tid < TM) { e_lds[tid] = 0.f; atom_l[tid] = perm[row0 + tid]; }
    const int atomR = perm[row0 + lr];
    float xsk = 0.f;
    if (atomR >= 0) {
      const float4* xrow = (const float4*)(X + (size_t)atomR * F);
      #pragma unroll
      for (int jj = 0; jj < 8; ++jj) {
        const int fi = lc + jj * 8;
        float4 v = xrow[fi];
        float4 wv = ((const float4*)wsk)[fi];
        xsk += v.x * wv.x + v.y * wv.y + v.z * wv.z + v.w * wv.w;
        *(ushort4*)&bufA[lr][fi * 4] =
            make_ushort4(f2bf(v.x), f2bf(v.y), f2bf(v.z), f2bf(v.w));
      }
    } else {
      #pragma unroll
      for (int jj = 0; jj < 8; ++jj)
        *(ushort4*)&bufA[lr][(lc + jj * 8) * 4] = make_ushort4(0, 0, 0, 0);
    }
    xskp[lr][lc] = xsk;
  }
  __syncthreads();

  const int w = tid >> 6, lane = tid & 63;
  const int l15 = lane & 15, lk = lane >> 4;
  f32x4 acc[4][2];

  // ---- GEMM1: h1 = tanh(X @ W1 + b1) -> bufB (bf16) ----
  gemm64(bufA, w1f, w, lane, acc);
  #pragma unroll
  for (int q = 0; q < 2; ++q) {
    const int col = (w * 2 + q) * 16 + l15;
    const float b1v = b1g[s * H + col];
    #pragma unroll
    for (int rt = 0; rt < 4; ++rt)
      #pragma unroll
      for (int r = 0; r < 4; ++r) {
        float h = tanh_fast(acc[rt][q][r] + b1v);
        bufB[rt * 16 + lk * 4 + r][col] = f2bf(h);
      }
  }
  __syncthreads();

  // ---- GEMM2: h2 = tanh(h1 @ W2 + b2); energy partials; d2 = (1-h2^2)*W3 -> bufA ----
  gemm64(bufB, w2f, w, lane, acc);
  {
    float ep[4][4];
    #pragma unroll
    for (int rt = 0; rt < 4; ++rt)
      #pragma unroll
      for (int r = 0; r < 4; ++r) ep[rt][r] = 0.f;
    #pragma unroll
    for (int q = 0; q < 2; ++q) {
      const int col = (w * 2 + q) * 16 + l15;
      const float b2v = b2g[s * H + col];
      const float w3v = W3g[s * H + col];
      #pragma unroll
      for (int rt = 0; rt < 4; ++rt)
        #pragma unroll
        for (int r = 0; r < 4; ++r) {
          float h = tanh_fast(acc[rt][q][r] + b2v);
          ep[rt][r] += h * w3v;
          bufA[rt * 16 + lk * 4 + r][col] = f2bf((1.f - h * h) * w3v);
        }
    }
    #pragma unroll
    for (int rt = 0; rt < 4; ++rt)
      #pragma unroll
      for (int r = 0; r < 4; ++r) {
        #pragma unroll
        for (int m = 1; m <= 8; m <<= 1)
          ep[rt][r] += __shfl_xor(ep[rt][r], m, 64);
      }
    if (l15 == 0) {
      #pragma unroll
      for (int rt = 0; rt < 4; ++rt)
        #pragma unroll
        for (int r = 0; r < 4; ++r)
          atomicAdd(&e_lds[rt * 16 + lk * 4 + r], ep[rt][r]);
    }
  }
  __syncthreads();

  // ---- energies finalize (64 threads) ----
  if (tid < TM) {
    int atom = atom_l[tid];
    if (atom >= 0) {
      float xs = 0.f;
      #pragma unroll
      for (int q = 0; q < 8; ++q) xs += xskp[tid][q];
      atomicAdd(&energies[smap[atom]], e_lds[tid] + xs + b3g[s] + bskipg[s]);
    }
  }

  // ---- GEMM3: g1 = d2 @ W2^T; d1 = (1-h1^2)*g1 -> bufB (h1 re-read in place) ----
  gemm64(bufA, w2tf, w, lane, acc);
  #pragma unroll
  for (int q = 0; q < 2; ++q) {
    const int col = (w * 2 + q) * 16 + l15;
    #pragma unroll
    for (int rt = 0; rt < 4; ++rt)
      #pragma unroll
      for (int r = 0; r < 4; ++r) {
        float h = bf2f(bufB[rt * 16 + lk * 4 + r][col]);
        bufB[rt * 16 + lk * 4 + r][col] = f2bf((1.f - h * h) * acc[rt][q][r]);
      }
  }
  __syncthreads();

  // ---- GEMM4: dE/dx = d1 @ W1^T + Wskip -> nng (bf16) ----
  gemm64(bufB, w1tf, w, lane, acc);
  #pragma unroll
  for (int q = 0; q < 2; ++q) {
    const int col = (w * 2 + q) * 16 + l15;
    const float wv = wsk[col];
    #pragma unroll
    for (int rt = 0; rt < 4; ++rt)
      #pragma unroll
      for (int r = 0; r < 4; ++r) {
        int atom2 = atom_l[rt * 16 + lk * 4 + r];
        if (atom2 >= 0) nng[(size_t)atom2 * F + col] = f2bf(acc[rt][q][r] + wv);
      }
  }
}

// ---------------- forces: one wave per pair ----------------

__global__ __launch_bounds__(256) void force_kernel(
    const float* __restrict__ ptg, const int* __restrict__ gmap,
    const unsigned short* __restrict__ g, float* __restrict__ forces, int P)
{
  int w = (int)((blockIdx.x * 256 + threadIdx.x) >> 6);
  int lane = threadIdx.x & 63;
  if (w >= P) return;
  int a = gmap[w];
  ushort4 gu = *(const ushort4*)(g + (size_t)a * F + lane * 4);
  float g0 = bf2f(gu.x), g1 = bf2f(gu.y), g2 = bf2f(gu.z), g3 = bf2f(gu.w);
  const float4* gr = (const float4*)(ptg + (size_t)w * 3 * F);
  float s0, s1, s2;
  {
    float4 t = gr[0 * 64 + lane];
    s0 = t.x * g0 + t.y * g1 + t.z * g2 + t.w * g3;
    t = gr[1 * 64 + lane];
    s1 = t.x * g0 + t.y * g1 + t.z * g2 + t.w * g3;
    t = gr[2 * 64 + lane];
    s2 = t.x * g0 + t.y * g1 + t.z * g2 + t.w * g3;
  }
  #pragma unroll
  for (int off = 32; off >= 1; off >>= 1) {
    s0 += __shfl_xor(s0, off, 64);
    s1 += __shfl_xor(s1, off, 64);
    s2 += __shfl_xor(s2, off, 64);
  }
  float r = (lane == 0) ? s0 : ((lane == 1) ? s1 : s2);
  if (lane < 3) atomicAdd(&forces[(size_t)a * 3 + lane], -r);
}

// ---------------- launch ----------------

extern "C" void kernel_launch(void* const* d_in, const int* in_sizes, int n_in,
                              void* d_out, int out_size, void* d_ws, size_t ws_size,
                              hipStream_t stream) {
  const float* X     = (const float*)d_in[0];
  const int*   z     = (const int*)d_in[1];
  const int*   smap  = (const int*)d_in[2];
  const float* ptg   = (const float*)d_in[3];
  const int*   gmap  = (const int*)d_in[4];
  const float* W1    = (const float*)d_in[5];
  const float* b1    = (const float*)d_in[6];
  const float* W2    = (const float*)d_in[7];
  const float* b2    = (const float*)d_in[8];
  const float* W3    = (const float*)d_in[9];
  const float* b3    = (const float*)d_in[10];
  const float* Wskip = (const float*)d_in[11];
  const float* bskip = (const float*)d_in[12];

  const int N = in_sizes[1];
  const int P = in_sizes[4];

  char* ws = (char*)d_ws;
  int* cnt  = (int*)ws;
  int* poff = (int*)(ws + 16);
  int* perm = (int*)(ws + 64);
  size_t perm_bytes = (size_t)(N + NSPEC * TM) * sizeof(int);
  size_t off = 64 + perm_bytes;
  off = (off + 255) & ~(size_t)255;
  unsigned short* Wf = (unsigned short*)(ws + off);
  const size_t WMAT = (size_t)NSPEC * 65536;
  off += 4 * WMAT * sizeof(unsigned short);
  off = (off + 255) & ~(size_t)255;
  unsigned short* nng = (unsigned short*)(ws + off);  // N * F bf16

  float* energies = (float*)d_out;
  float* forces   = energies + NSTRUCT;

  hipMemsetAsync(d_out, 0, (size_t)out_size * sizeof(float), stream);
  hipMemsetAsync(cnt, 0, 16, stream);
  hipMemsetAsync(perm, 0xFF, perm_bytes, stream);

  prep_w<<<(4 * NSPEC * 8192 + 255) / 256, 256, 0, stream>>>(W1, W2, Wf);

  histogram_kernel<<<(N + 255) / 256, 256, 0, stream>>>(z, cnt, N);
  scan_kernel<<<1, 1, 0, stream>>>(cnt, poff);
  scatter_kernel<<<(N + 255) / 256, 256, 0, stream>>>(z, poff, cnt, perm, N);

  int mlpBlocks = (N + TM - 1) / TM + NSPEC;
  mlp_fused<<<mlpBlocks, 512, 0, stream>>>(X, smap, Wf, b1, b2, W3, b3,
                                           Wskip, bskip, perm, poff,
                                           energies, nng);

  int forceBlocks = (int)(((size_t)P * 64 + 255) / 256);
  force_kernel<<<forceBlocks, 256, 0, stream>>>(ptg, gmap, nng, forces, P);
}